// Round 2
// baseline (99.757 us; speedup 1.0000x reference)
//
#include <hip/hip_runtime.h>
#include <math.h>

// Problem constants
#define NSLOT 64
#define ADIM  256
#define NE    16
#define NCLS  100
#define BATCH 256

// ws layout (float offsets)
#define OFF_QK 0u           // [16][256][4]  qk[e][a][l], pre-scaled by 1/16
#define OFF_CP 16384u       // [16]          log1p(count+1)
#define OFF_U  32768u       // [256*16][256] u[(b*16+e)][a]
#define OFF_Z  1081344u     // [256*16][256] z[(b*16+e)][d]

__device__ __forceinline__ float wmax(float v) {
#pragma unroll
  for (int m = 32; m >= 1; m >>= 1) v = fmaxf(v, __shfl_xor(v, m, 64));
  return v;
}
__device__ __forceinline__ float wsum(float v) {
#pragma unroll
  for (int m = 32; m >= 1; m >>= 1) v += __shfl_xor(v, m, 64);
  return v;
}

// ---------------- K1: qk[e][a][l] = (1/16) * sum_d queries[e,l,d]*Wk[e,d,a]
__global__ __launch_bounds__(256) void prep_kernel(
    const float* __restrict__ queries, const float* __restrict__ Wk,
    const int* __restrict__ counts, float* __restrict__ qk, float* __restrict__ cp)
{
  const int e = blockIdx.x;
  const int l = blockIdx.y;
  const int a = threadIdx.x;
  const float* __restrict__ q   = queries + (e * 4 + l) * 256;
  const float* __restrict__ wkp = Wk + (size_t)e * 65536 + a;
  float acc = 0.f;
#pragma unroll 8
  for (int d = 0; d < 256; ++d)
    acc += q[d] * wkp[(size_t)d * 256];
  qk[e * 1024 + a * 4 + l] = acc * 0.0625f;
  if (e == 0 && l == 0 && a < 16) cp[a] = log1pf((float)counts[a] + 1.0f);
}

// ---------------- K2: per batch b: scores (16 experts) -> softmax -> p -> u
// Hs chunk-swizzled: float4-chunk c of row s stored at chunk (c ^ (s&7)).
__global__ __launch_bounds__(256) void attn_kernel(
    const float* __restrict__ x, const float* __restrict__ qk,
    float* __restrict__ U)
{
  __shared__ float Hs[64][256];   // swizzled
  __shared__ float pt[64][20];    // p[s][e], padded stride 20
  const int tid   = threadIdx.x;
  const int lane  = tid & 63;
  const int w     = tid >> 6;
  const int b     = blockIdx.x;

  // stage H[b] into LDS (swizzled). Wave writes one row per iter: chunks = perm.
  const float4* __restrict__ x4 = (const float4*)(x + (size_t)b * 16384);
#pragma unroll
  for (int i = 0; i < 16; ++i) {
    int fidx = tid + i * 256;           // 0..4095 float4s
    int s = fidx >> 6, c = fidx & 63;
    *(float4*)&Hs[s][(c ^ (s & 7)) << 2] = x4[fidx];
  }
  __syncthreads();

  // score phase: wave w handles experts 4w..4w+3; lane = slot s
  {
    const int e0 = __builtin_amdgcn_readfirstlane(4 * w);
    const float* __restrict__ q0 = qk + (size_t)(e0 + 0) * 1024;
    const float* __restrict__ q1 = qk + (size_t)(e0 + 1) * 1024;
    const float* __restrict__ q2 = qk + (size_t)(e0 + 2) * 1024;
    const float* __restrict__ q3 = qk + (size_t)(e0 + 3) * 1024;
    float acc[4][4] = {};
#pragma unroll 4
    for (int a0 = 0; a0 < 64; ++a0) {
      float4 h = *(const float4*)&Hs[lane][(a0 ^ (lane & 7)) << 2];
      const float* qp[4] = { q0 + a0 * 16, q1 + a0 * 16, q2 + a0 * 16, q3 + a0 * 16 };
#pragma unroll
      for (int k = 0; k < 4; ++k) {
        const float4* pq = (const float4*)qp[k];
        float4 qa = pq[0], qb = pq[1], qc = pq[2], qd = pq[3];
        acc[k][0] += h.x*qa.x + h.y*qb.x + h.z*qc.x + h.w*qd.x;
        acc[k][1] += h.x*qa.y + h.y*qb.y + h.z*qc.y + h.w*qd.y;
        acc[k][2] += h.x*qa.z + h.y*qb.z + h.z*qc.z + h.w*qd.z;
        acc[k][3] += h.x*qa.w + h.y*qb.w + h.z*qc.w + h.w*qd.w;
      }
    }
#pragma unroll
    for (int k = 0; k < 4; ++k) {
      float p = 0.f;
#pragma unroll
      for (int l = 0; l < 4; ++l) {
        float m  = wmax(acc[k][l]);
        float ev = __expf(acc[k][l] - m);
        p += ev / wsum(ev);
      }
      pt[lane][4 * w + k] = p * 0.25f;
    }
  }
  __syncthreads();

  // u phase: thread a accumulates u for all 16 experts
  {
    const int a = tid;
    const int cswz = ((a >> 2) << 2);   // base chunk*4
    const int rem  = a & 3;
    float u[16] = {};
#pragma unroll 8
    for (int s = 0; s < 64; ++s) {
      float h = Hs[s][((((a >> 2) ^ (s & 7)) << 2) | rem)];
      float4 p0 = *(const float4*)&pt[s][0];
      float4 p1 = *(const float4*)&pt[s][4];
      float4 p2 = *(const float4*)&pt[s][8];
      float4 p3 = *(const float4*)&pt[s][12];
      u[0]+=h*p0.x; u[1]+=h*p0.y; u[2]+=h*p0.z; u[3]+=h*p0.w;
      u[4]+=h*p1.x; u[5]+=h*p1.y; u[6]+=h*p1.z; u[7]+=h*p1.w;
      u[8]+=h*p2.x; u[9]+=h*p2.y; u[10]+=h*p2.z; u[11]+=h*p2.w;
      u[12]+=h*p3.x; u[13]+=h*p3.y; u[14]+=h*p3.z; u[15]+=h*p3.w;
    }
    float* __restrict__ Ub = U + ((size_t)b * 16) * 256 + a;
#pragma unroll
    for (int e = 0; e < 16; ++e) Ub[e * 256] = u[e];
    (void)cswz;
  }
}

// ---------------- K3: per-expert GEMM  z[b,e,:] = u[b,e,:] @ Wv[e]^T
// Tiles chunk-swizzled: chunk c of row r stored at chunk (c ^ ((r>>2)&7)).
__global__ __launch_bounds__(256) void zgemm_kernel(
    const float* __restrict__ U, const float* __restrict__ Wv,
    float* __restrict__ Z)
{
  __shared__ float Us[64][64];
  __shared__ float Ws[64][64];
  const int tid = threadIdx.x;
  const int e  = blockIdx.y;
  const int bt = blockIdx.x >> 2, dt = blockIdx.x & 3;
  const int tx = tid & 15, ty = tid >> 4;
  float acc[4][4] = {};

  for (int ck = 0; ck < 4; ++ck) {
#pragma unroll
    for (int i = 0; i < 4; ++i) {
      int t2 = tid + i * 256;           // 0..1023
      int row = t2 >> 4, c = t2 & 15;
      int cs = (c ^ ((row >> 2) & 7)) << 2;
      *(float4*)&Us[row][cs] =
        *(const float4*)&U[(((size_t)(bt * 64 + row)) * 16 + e) * 256 + ck * 64 + c * 4];
      *(float4*)&Ws[row][cs] =
        *(const float4*)&Wv[(size_t)e * 65536 + (size_t)(dt * 64 + row) * 256 + ck * 64 + c * 4];
    }
    __syncthreads();
#pragma unroll
    for (int cc = 0; cc < 16; ++cc) {
      float4 A[4], B[4];
#pragma unroll
      for (int i = 0; i < 4; ++i) A[i] = *(const float4*)&Us[ty * 4 + i][(cc ^ (ty & 7)) << 2];
#pragma unroll
      for (int j = 0; j < 4; ++j) B[j] = *(const float4*)&Ws[tx * 4 + j][(cc ^ (tx & 7)) << 2];
#pragma unroll
      for (int i = 0; i < 4; ++i)
#pragma unroll
        for (int j = 0; j < 4; ++j)
          acc[i][j] += A[i].x*B[j].x + A[i].y*B[j].y + A[i].z*B[j].z + A[i].w*B[j].w;
    }
    __syncthreads();
  }
#pragma unroll
  for (int i = 0; i < 4; ++i) {
    float4 r; r.x = acc[i][0]; r.y = acc[i][1]; r.z = acc[i][2]; r.w = acc[i][3];
    *(float4*)&Z[(((size_t)(bt * 64 + ty * 4 + i)) * 16 + e) * 256 + dt * 64 + tx * 4] = r;
  }
}

// ---------------- K4: norms -> top3 -> gate -> final -> logits
__global__ __launch_bounds__(256) void final_kernel(
    const float* __restrict__ Z, const float* __restrict__ cp,
    const float* __restrict__ CQ, float* __restrict__ out)
{
  __shared__ float nrm[16];
  __shared__ float fin[256];
  const int tid = threadIdx.x, lane = tid & 63, w = tid >> 6;
  const int b = blockIdx.x;
  const size_t zb = (size_t)b * 16 * 256;

  for (int e = w; e < 16; e += 4) {
    float4 zv = *(const float4*)&Z[zb + (size_t)e * 256 + lane * 4];
    float ss = zv.x*zv.x + zv.y*zv.y + zv.z*zv.z + zv.w*zv.w;
    ss = wsum(ss);
    if (lane == 0) nrm[e] = sqrtf(ss);
  }
  __syncthreads();

  float sc[16];
#pragma unroll
  for (int e = 0; e < 16; ++e) sc[e] = nrm[e] * cp[e];
  int i0 = 0; float v0 = sc[0];
#pragma unroll
  for (int e = 1; e < 16; ++e) if (sc[e] > v0) { v0 = sc[e]; i0 = e; }
  int i1 = -1; float v1 = -3.4e38f;
#pragma unroll
  for (int e = 0; e < 16; ++e) if (e != i0 && sc[e] > v1) { v1 = sc[e]; i1 = e; }
  int i2 = -1; float v2 = -3.4e38f;
#pragma unroll
  for (int e = 0; e < 16; ++e) if (e != i0 && e != i1 && sc[e] > v2) { v2 = sc[e]; i2 = e; }
  float g1 = __expf(v1 - v0), g2 = __expf(v2 - v0);
  float inv = 1.0f / (1.0f + g1 + g2);
  float g0 = inv; g1 *= inv; g2 *= inv;

  fin[tid] = g0 * Z[zb + (size_t)i0 * 256 + tid]
           + g1 * Z[zb + (size_t)i1 * 256 + tid]
           + g2 * Z[zb + (size_t)i2 * 256 + tid];
  __syncthreads();

  float4 f = *(const float4*)&fin[lane * 4];
  for (int c = w; c < NCLS; c += 4) {
    float4 cq = *(const float4*)&CQ[(size_t)c * 256 + lane * 4];
    float part = f.x*cq.x + f.y*cq.y + f.z*cq.z + f.w*cq.w;
    part = wsum(part);
    if (lane == 0) out[(size_t)b * NCLS + c] = part;
  }
}

extern "C" void kernel_launch(void* const* d_in, const int* in_sizes, int n_in,
                              void* d_out, int out_size, void* d_ws, size_t ws_size,
                              hipStream_t stream) {
  const float* x       = (const float*)d_in[0];
  const float* queries = (const float*)d_in[1];
  const float* Wk      = (const float*)d_in[2];
  const float* Wv      = (const float*)d_in[3];
  const float* CQ      = (const float*)d_in[4];
  const int*   counts  = (const int*)d_in[5];
  float* out = (float*)d_out;
  float* ws  = (float*)d_ws;
  float* qk = ws + OFF_QK;
  float* cp = ws + OFF_CP;
  float* U  = ws + OFF_U;
  float* Z  = ws + OFF_Z;

  prep_kernel<<<dim3(16, 4), 256, 0, stream>>>(queries, Wk, counts, qk, cp);
  attn_kernel<<<256, 256, 0, stream>>>(x, qk, U);
  zgemm_kernel<<<dim3(16, 16), 256, 0, stream>>>(U, Wv, Z);
  final_kernel<<<256, 256, 0, stream>>>(Z, cp, CQ, out);
}

// Round 3
// 74.221 us; speedup vs baseline: 1.3440x; 1.3440x over previous
//
#include <hip/hip_runtime.h>
#include <math.h>

// Problem constants
#define NSLOT 64
#define ADIM  256
#define NE    16
#define NCLS  100
#define BATCH 256

// ws layout (float offsets)
#define OFF_QK 0u           // [16][256][4]  qk[e][a][l], pre-scaled by 1/16 (atomicAdd target)
#define OFF_CP 16384u       // [16]          log1p(count+1)
#define OFF_U  32768u       // [256*16][256] u[(b*16+e)][a]
#define OFF_Z  1081344u     // [256*16][256] z[(b*16+e)][d]

__device__ __forceinline__ float wmax(float v) {
#pragma unroll
  for (int m = 32; m >= 1; m >>= 1) v = fmaxf(v, __shfl_xor(v, m, 64));
  return v;
}
__device__ __forceinline__ float wsum(float v) {
#pragma unroll
  for (int m = 32; m >= 1; m >>= 1) v += __shfl_xor(v, m, 64);
  return v;
}

// ---------------- K1: qk[e][a][l] += (1/16) * sum_{d in chunk} q[e,l,d]*Wk[e,d,a]
// grid (16 e, 16 chunks of 16 d). Wk read exactly once, coalesced.
__global__ __launch_bounds__(256) void prep_kernel(
    const float* __restrict__ queries, const float* __restrict__ Wk,
    const int* __restrict__ counts, float* __restrict__ qk, float* __restrict__ cp)
{
  const int e  = blockIdx.x;
  const int ch = blockIdx.y;
  const int a  = threadIdx.x;
  const float* __restrict__ qp  = queries + e * 1024 + ch * 16;     // [l*256 + dd]
  const float* __restrict__ wkp = Wk + (size_t)e * 65536 + (size_t)(ch * 16) * 256 + a;
  float a0 = 0.f, a1 = 0.f, a2 = 0.f, a3 = 0.f;
#pragma unroll
  for (int dd = 0; dd < 16; ++dd) {
    float w = wkp[(size_t)dd * 256];
    a0 += qp[0 * 256 + dd] * w;
    a1 += qp[1 * 256 + dd] * w;
    a2 += qp[2 * 256 + dd] * w;
    a3 += qp[3 * 256 + dd] * w;
  }
  float* dst = qk + e * 1024 + a * 4;
  atomicAdd(dst + 0, a0 * 0.0625f);
  atomicAdd(dst + 1, a1 * 0.0625f);
  atomicAdd(dst + 2, a2 * 0.0625f);
  atomicAdd(dst + 3, a3 * 0.0625f);
  if (e == 0 && ch == 0 && a < 16) cp[a] = log1pf((float)counts[a] + 1.0f);
}

// ---------------- K2: per (b, expert-half): scores -> softmax -> p -> u
// 512 blocks -> 2 blocks/CU (LDS 66KB), 8 waves/CU.
__global__ __launch_bounds__(256, 2) void attn_kernel(
    const float* __restrict__ x, const float* __restrict__ qk,
    float* __restrict__ U)
{
  __shared__ float Hs[64][256];   // chunk-swizzled: chunk c of row s at (c ^ (s&7))
  __shared__ float pt[64][8];     // p[s][e_local]
  const int tid   = threadIdx.x;
  const int lane  = tid & 63;
  const int w     = tid >> 6;
  const int b     = blockIdx.x >> 1;
  const int ebase = (blockIdx.x & 1) * 8;

  // stage H[b] into LDS (swizzled)
  const float4* __restrict__ x4 = (const float4*)(x + (size_t)b * 16384);
#pragma unroll
  for (int i = 0; i < 16; ++i) {
    int fidx = tid + i * 256;           // 0..4095 float4s
    int s = fidx >> 6, c = fidx & 63;
    *(float4*)&Hs[s][(c ^ (s & 7)) << 2] = x4[fidx];
  }
  __syncthreads();

  // score phase: wave w handles experts ebase+w (A) and ebase+w+4 (B); lane = slot s
  {
    const int es0 = __builtin_amdgcn_readfirstlane(ebase + w);
    const int es1 = __builtin_amdgcn_readfirstlane(ebase + w + 4);
    const float* __restrict__ qA = qk + (size_t)es0 * 1024;
    const float* __restrict__ qB = qk + (size_t)es1 * 1024;
    float aA0=0,aA1=0,aA2=0,aA3=0,aB0=0,aB1=0,aB2=0,aB3=0;
#pragma unroll 4
    for (int a0 = 0; a0 < 64; ++a0) {
      float4 h = *(const float4*)&Hs[lane][(a0 ^ (lane & 7)) << 2];
      const float4* pa = (const float4*)(qA + a0 * 16);
      const float4* pb = (const float4*)(qB + a0 * 16);
      float4 qa0 = pa[0], qa1 = pa[1], qa2 = pa[2], qa3 = pa[3];
      float4 qb0 = pb[0], qb1 = pb[1], qb2 = pb[2], qb3 = pb[3];
      aA0 += h.x*qa0.x + h.y*qa1.x + h.z*qa2.x + h.w*qa3.x;
      aA1 += h.x*qa0.y + h.y*qa1.y + h.z*qa2.y + h.w*qa3.y;
      aA2 += h.x*qa0.z + h.y*qa1.z + h.z*qa2.z + h.w*qa3.z;
      aA3 += h.x*qa0.w + h.y*qa1.w + h.z*qa2.w + h.w*qa3.w;
      aB0 += h.x*qb0.x + h.y*qb1.x + h.z*qb2.x + h.w*qb3.x;
      aB1 += h.x*qb0.y + h.y*qb1.y + h.z*qb2.y + h.w*qb3.y;
      aB2 += h.x*qb0.z + h.y*qb1.z + h.z*qb2.z + h.w*qb3.z;
      aB3 += h.x*qb0.w + h.y*qb1.w + h.z*qb2.w + h.w*qb3.w;
    }
    float pA = 0.f, pB = 0.f, m, ev;
    m = wmax(aA0); ev = __expf(aA0 - m); pA += ev / wsum(ev);
    m = wmax(aA1); ev = __expf(aA1 - m); pA += ev / wsum(ev);
    m = wmax(aA2); ev = __expf(aA2 - m); pA += ev / wsum(ev);
    m = wmax(aA3); ev = __expf(aA3 - m); pA += ev / wsum(ev);
    m = wmax(aB0); ev = __expf(aB0 - m); pB += ev / wsum(ev);
    m = wmax(aB1); ev = __expf(aB1 - m); pB += ev / wsum(ev);
    m = wmax(aB2); ev = __expf(aB2 - m); pB += ev / wsum(ev);
    m = wmax(aB3); ev = __expf(aB3 - m); pB += ev / wsum(ev);
    pt[lane][w]     = pA * 0.25f;
    pt[lane][w + 4] = pB * 0.25f;
  }
  __syncthreads();

  // u phase: thread a accumulates u for this half's 8 experts
  {
    const int a = tid;
    const int hi = a >> 2, rem = a & 3;
    float u0=0,u1=0,u2=0,u3=0,u4=0,u5=0,u6=0,u7=0;
#pragma unroll 8
    for (int s = 0; s < 64; ++s) {
      float h = Hs[s][(((hi ^ (s & 7)) << 2) | rem)];
      float4 p0 = *(const float4*)&pt[s][0];
      float4 p1 = *(const float4*)&pt[s][4];
      u0 += h * p0.x; u1 += h * p0.y; u2 += h * p0.z; u3 += h * p0.w;
      u4 += h * p1.x; u5 += h * p1.y; u6 += h * p1.z; u7 += h * p1.w;
    }
    float* __restrict__ Ub = U + ((size_t)b * 16 + ebase) * 256 + a;
    Ub[0*256]=u0; Ub[1*256]=u1; Ub[2*256]=u2; Ub[3*256]=u3;
    Ub[4*256]=u4; Ub[5*256]=u5; Ub[6*256]=u6; Ub[7*256]=u7;
  }
}

// ---------------- K3: per-expert GEMM  z[b,e,:] = u[b,e,:] @ Wv[e]^T
// 64(b) x 32(d) tiles, grid (32, 16e) = 512 blocks -> 2 blocks/CU.
__global__ __launch_bounds__(256, 2) void zgemm_kernel(
    const float* __restrict__ U, const float* __restrict__ Wv,
    float* __restrict__ Z)
{
  __shared__ float Us[64][64];   // rows = b-tile, cols = k-chunk (swizzled)
  __shared__ float Ws[32][64];   // rows = d-tile, cols = k-chunk (swizzled)
  const int tid = threadIdx.x;
  const int e  = blockIdx.y;
  const int bt = blockIdx.x >> 3, dt = blockIdx.x & 7;
  const int tx = tid & 15, ty = tid >> 4;
  float acc[4][2] = {};

  for (int ck = 0; ck < 4; ++ck) {
#pragma unroll
    for (int i = 0; i < 4; ++i) {
      int t2 = tid + i * 256;           // 0..1023
      int row = t2 >> 4, c = t2 & 15;
      int cs = (c ^ ((row >> 2) & 7)) << 2;
      *(float4*)&Us[row][cs] =
        *(const float4*)&U[(((size_t)(bt * 64 + row)) * 16 + e) * 256 + ck * 64 + c * 4];
    }
#pragma unroll
    for (int i = 0; i < 2; ++i) {
      int t2 = tid + i * 256;           // 0..511
      int row = t2 >> 4, c = t2 & 15;
      int cs = (c ^ ((row >> 2) & 7)) << 2;
      *(float4*)&Ws[row][cs] =
        *(const float4*)&Wv[(size_t)e * 65536 + (size_t)(dt * 32 + row) * 256 + ck * 64 + c * 4];
    }
    __syncthreads();
#pragma unroll
    for (int cc = 0; cc < 16; ++cc) {
      float4 A[4], B[2];
#pragma unroll
      for (int i = 0; i < 4; ++i) A[i] = *(const float4*)&Us[ty * 4 + i][(cc ^ (ty & 7)) << 2];
#pragma unroll
      for (int j = 0; j < 2; ++j) B[j] = *(const float4*)&Ws[tx * 2 + j][(cc ^ ((tx >> 1) & 7)) << 2];
#pragma unroll
      for (int i = 0; i < 4; ++i)
#pragma unroll
        for (int j = 0; j < 2; ++j)
          acc[i][j] += A[i].x*B[j].x + A[i].y*B[j].y + A[i].z*B[j].z + A[i].w*B[j].w;
    }
    __syncthreads();
  }
#pragma unroll
  for (int i = 0; i < 4; ++i) {
    float2 r; r.x = acc[i][0]; r.y = acc[i][1];
    *(float2*)&Z[(((size_t)(bt * 64 + ty * 4 + i)) * 16 + e) * 256 + dt * 32 + tx * 2] = r;
  }
}

// ---------------- K4: norms -> top3 -> gate -> final -> logits
__global__ __launch_bounds__(256) void final_kernel(
    const float* __restrict__ Z, const float* __restrict__ cp,
    const float* __restrict__ CQ, float* __restrict__ out)
{
  __shared__ float nrm[16];
  __shared__ float fin[256];
  const int tid = threadIdx.x, lane = tid & 63, w = tid >> 6;
  const int b = blockIdx.x;
  const size_t zb = (size_t)b * 16 * 256;

  for (int e = w; e < 16; e += 4) {
    float4 zv = *(const float4*)&Z[zb + (size_t)e * 256 + lane * 4];
    float ss = zv.x*zv.x + zv.y*zv.y + zv.z*zv.z + zv.w*zv.w;
    ss = wsum(ss);
    if (lane == 0) nrm[e] = sqrtf(ss);
  }
  __syncthreads();

  float sc[16];
#pragma unroll
  for (int e = 0; e < 16; ++e) sc[e] = nrm[e] * cp[e];
  int i0 = 0; float v0 = sc[0];
#pragma unroll
  for (int e = 1; e < 16; ++e) if (sc[e] > v0) { v0 = sc[e]; i0 = e; }
  int i1 = -1; float v1 = -3.4e38f;
#pragma unroll
  for (int e = 0; e < 16; ++e) if (e != i0 && sc[e] > v1) { v1 = sc[e]; i1 = e; }
  int i2 = -1; float v2 = -3.4e38f;
#pragma unroll
  for (int e = 0; e < 16; ++e) if (e != i0 && e != i1 && sc[e] > v2) { v2 = sc[e]; i2 = e; }
  float g1 = __expf(v1 - v0), g2 = __expf(v2 - v0);
  float inv = 1.0f / (1.0f + g1 + g2);
  float g0 = inv; g1 *= inv; g2 *= inv;

  fin[tid] = g0 * Z[zb + (size_t)i0 * 256 + tid]
           + g1 * Z[zb + (size_t)i1 * 256 + tid]
           + g2 * Z[zb + (size_t)i2 * 256 + tid];
  __syncthreads();

  float4 f = *(const float4*)&fin[lane * 4];
  for (int c = w; c < NCLS; c += 4) {
    float4 cq = *(const float4*)&CQ[(size_t)c * 256 + lane * 4];
    float part = f.x*cq.x + f.y*cq.y + f.z*cq.z + f.w*cq.w;
    part = wsum(part);
    if (lane == 0) out[(size_t)b * NCLS + c] = part;
  }
}

extern "C" void kernel_launch(void* const* d_in, const int* in_sizes, int n_in,
                              void* d_out, int out_size, void* d_ws, size_t ws_size,
                              hipStream_t stream) {
  const float* x       = (const float*)d_in[0];
  const float* queries = (const float*)d_in[1];
  const float* Wk      = (const float*)d_in[2];
  const float* Wv      = (const float*)d_in[3];
  const float* CQ      = (const float*)d_in[4];
  const int*   counts  = (const int*)d_in[5];
  float* out = (float*)d_out;
  float* ws  = (float*)d_ws;
  float* qk = ws + OFF_QK;
  float* cp = ws + OFF_CP;
  float* U  = ws + OFF_U;
  float* Z  = ws + OFF_Z;

  hipMemsetAsync(qk, 0, 16384 * sizeof(float), stream);
  prep_kernel<<<dim3(16, 16), 256, 0, stream>>>(queries, Wk, counts, qk, cp);
  attn_kernel<<<512, 256, 0, stream>>>(x, qk, U);
  zgemm_kernel<<<dim3(32, 16), 256, 0, stream>>>(U, Wv, Z);
  final_kernel<<<256, 256, 0, stream>>>(Z, cp, CQ, out);
}